// Round 5
// baseline (35205.066 us; speedup 1.0000x reference)
//
#include <hip/hip_runtime.h>
#include <hip/hip_bf16.h>

// LSTM autoencoder, batch-partitioned: 4 layers x 4 row-groups = 16 WGs of
// 1024 threads (16 waves, 1 CU each; VGPR use forces 1 WG/CU). Each WG holds
// its layer's FULL W,U as register MFMA B-fragments spread over 16 waves and
// owns 16 batch rows -> the recurrence is WG-LOCAL (LDS ping-pong + one
// __syncthreads per step; no cross-WG sync on the serial chain). Layer->layer
// handoff is forward-only, chunked (C=8 steps) through a D=4-slot global ring
// with relaxed agent-scope atomics + per-chunk produced/consumed flags.

typedef __bf16 bf16x8 __attribute__((ext_vector_type(8)));
typedef float f32x4 __attribute__((ext_vector_type(4)));
typedef unsigned long long u64;

#define TSTEPS 1024
#define CCH 8          // timesteps per chunk
#define DSLOT 4        // ring depth in chunks
#define NCHUNK (TSTEPS / CCH)

__device__ __forceinline__ f32x4 mfma16(bf16x8 a, bf16x8 b, f32x4 c) {
  return __builtin_amdgcn_mfma_f32_16x16x32_bf16(a, b, c, 0, 0, 0);
}

__device__ __forceinline__ float sigmoid_fast(float x) {
  return 1.0f / (1.0f + __expf(-x));
}

__device__ __forceinline__ u64 load8_llc(const __bf16* p) {
  return __hip_atomic_load((const u64*)p, __ATOMIC_RELAXED,
                           __HIP_MEMORY_SCOPE_AGENT);
}
__device__ __forceinline__ void store8_llc(__bf16* p, u64 v) {
  __hip_atomic_store((u64*)p, v, __ATOMIC_RELAXED, __HIP_MEMORY_SCOPE_AGENT);
}

// flag index: ((iface*2 + kind)*4 + rg) * 32   kind: 0=produced, 1=consumed
__device__ __forceinline__ unsigned* flag_ptr(unsigned* f, int iface, int kind,
                                              int rg) {
  return &f[((iface * 2 + kind) * 4 + rg) * 32];
}

// One layer, one batch row-group (16 rows). 16 waves; wave w owns h-cols
// [w*16, w*16+16) across all 4 gates (4 n-tiles). Weights in registers.
template <int F, int H, int LAYER>
__device__ void layer_run(const float* __restrict__ xg,   // L1: x [64][1024][256]
                          const __bf16* __restrict__ rin, // L>1: ring in
                          const float* __restrict__ W, const float* __restrict__ U,
                          const float* __restrict__ bias,
                          __bf16* __restrict__ rout,      // L<4: ring out
                          float* __restrict__ out,        // L4
                          unsigned* flags, int rg, char* lds) {
  constexpr int KW = F / 32;
  constexpr int KU = H / 32;
  constexpr int NW = H / 16;      // active waves
  constexpr int HP = H + 8;       // padded LDS row stride (bank-conflict fix)
  constexpr int FOURH = 4 * H;
  const int tid = threadIdx.x;
  const int wave = tid >> 6;
  const int lane = tid & 63;
  const int l15 = lane & 15;
  const int q = lane >> 4;
  const int hbase = wave * 16;

  __bf16* slab = (__bf16*)lds;                       // 32 KB staging
  __bf16* hb = (__bf16*)(lds + 32768);               // 2 x 16 x HP ping-pong

  // ---- one-time: stage W,U per wave-round, extract B-frags to registers ----
  bf16x8 wf[4][KW];
  bf16x8 uf[4][KU];
  for (int r = 0; r < NW; ++r) {
    for (int idx = tid; idx < F * 64; idx += 1024) {
      int k = idx >> 6, c = idx & 63;
      int col = (c >> 4) * H + r * 16 + (c & 15);
      slab[c * F + k] = (__bf16)W[k * FOURH + col];
    }
    __syncthreads();
    if (wave == r) {
#pragma unroll
      for (int nt = 0; nt < 4; ++nt)
#pragma unroll
        for (int kk = 0; kk < KW; ++kk)
          wf[nt][kk] = *(const bf16x8*)&slab[(nt * 16 + l15) * F + kk * 32 + q * 8];
    }
    __syncthreads();
  }
  for (int r = 0; r < NW; ++r) {
    for (int idx = tid; idx < H * 64; idx += 1024) {
      int k = idx >> 6, c = idx & 63;
      int col = (c >> 4) * H + r * 16 + (c & 15);
      slab[c * H + k] = (__bf16)U[k * FOURH + col];
    }
    __syncthreads();
    if (wave == r) {
#pragma unroll
      for (int nt = 0; nt < 4; ++nt)
#pragma unroll
        for (int kk = 0; kk < KU; ++kk)
          uf[nt][kk] = *(const bf16x8*)&slab[(nt * 16 + l15) * H + kk * 32 + q * 8];
    }
    __syncthreads();
  }

  float bz[4];
  if (wave < NW) {
#pragma unroll
    for (int nt = 0; nt < 4; ++nt) bz[nt] = bias[nt * H + hbase + l15];
  }

  float c_state[4] = {0.f, 0.f, 0.f, 0.f};

  for (int k = 0; k < NCHUNK; ++k) {
    // ---- chunk-boundary flag poll (wave 0 only) ----
    if (wave == 0) {
      unsigned* fp = nullptr;
      unsigned tgt = 0;
      if (LAYER > 1 && lane == 0) {                 // input chunk produced?
        fp = flag_ptr(flags, LAYER - 2, 0, rg);
        tgt = (unsigned)(k + 1);
      }
      if (LAYER < 4 && lane == 1) {                 // our ring slot consumed?
        int tc = k + 1 - DSLOT;
        if (tc > 0) { fp = flag_ptr(flags, LAYER - 1, 1, rg); tgt = (unsigned)tc; }
      }
      const bool need = (fp != nullptr);
      while (true) {
        unsigned v = need ? __hip_atomic_load(fp, __ATOMIC_RELAXED,
                                              __HIP_MEMORY_SCOPE_AGENT)
                          : 0xFFFFFFFFu;
        if (!__ballot(need && v < tgt)) break;
      }
    }
    __syncthreads();

    const int slot = k & (DSLOT - 1);

    for (int i = 0; i < CCH; ++i) {
      const int t = k * CCH + i;
      const int cur = t & 1, prv = cur ^ 1;

      // ---- issue input loads early (latency hides under h@U MFMAs) ----
      float4 rawx[(LAYER == 1) ? 2 * KW : 1];
      u64 rawr[(LAYER > 1) ? 2 * KW : 1];
      if (wave < NW) {
        if (LAYER == 1) {
          const float* xr = xg + ((size_t)(rg * 16 + l15) * 1024 + t) * 256 + q * 8;
#pragma unroll
          for (int kk = 0; kk < KW; ++kk) {
            const float4* p4 = (const float4*)(xr + kk * 32);
            rawx[2 * kk] = p4[0];
            rawx[2 * kk + 1] = p4[1];
          }
        } else {
          const __bf16* xr = rin + ((size_t)(rg * DSLOT + slot) * CCH + i) * 16 * F +
                             l15 * F + q * 8;
#pragma unroll
          for (int kk = 0; kk < KW; ++kk) {
            rawr[2 * kk] = load8_llc(xr + kk * 32);
            rawr[2 * kk + 1] = load8_llc(xr + kk * 32 + 4);
          }
        }
      }

      float hv[4];
      if (wave < NW) {
        f32x4 acc[4] = {};
        // ---- recurrent projection first: z += h(t-1) @ U (LDS) ----
        if (t > 0) {
#pragma unroll
          for (int kk = 0; kk < KU; ++kk) {
            bf16x8 a = *(const bf16x8*)&hb[prv * 16 * HP + l15 * HP + kk * 32 + q * 8];
#pragma unroll
            for (int nt = 0; nt < 4; ++nt) acc[nt] = mfma16(a, uf[nt][kk], acc[nt]);
          }
        }
        // ---- input projection: z += x(t) @ W ----
#pragma unroll
        for (int kk = 0; kk < KW; ++kk) {
          bf16x8 a;
          if (LAYER == 1) {
            float4 a0 = rawx[2 * kk], a1 = rawx[2 * kk + 1];
            a[0] = (__bf16)a0.x; a[1] = (__bf16)a0.y;
            a[2] = (__bf16)a0.z; a[3] = (__bf16)a0.w;
            a[4] = (__bf16)a1.x; a[5] = (__bf16)a1.y;
            a[6] = (__bf16)a1.z; a[7] = (__bf16)a1.w;
          } else {
            union { bf16x8 v; u64 d[2]; } u;
            u.d[0] = rawr[2 * kk]; u.d[1] = rawr[2 * kk + 1];
            a = u.v;
          }
#pragma unroll
          for (int nt = 0; nt < 4; ++nt) acc[nt] = mfma16(a, wf[nt][kk], acc[nt]);
        }
        // ---- gates + state update (lane-local) ----
#pragma unroll
        for (int r = 0; r < 4; ++r) {
          float zi = acc[0][r] + bz[0];
          float zf = acc[1][r] + bz[1];
          float zg = acc[2][r] + bz[2];
          float zo = acc[3][r] + bz[3];
          float ig = sigmoid_fast(zi);
          float fg = sigmoid_fast(zf);
          float gg = fmaxf(zg, 0.0f);
          float og = sigmoid_fast(zo);
          float cn = fg * c_state[r] + ig * gg;
          c_state[r] = cn;
          hv[r] = og * fmaxf(cn, 0.0f);
          hb[cur * 16 * HP + (q * 4 + r) * HP + hbase + l15] = (__bf16)hv[r];
          if (LAYER == 4)
            out[((size_t)(rg * 16 + q * 4 + r) * 1024 + t) * 256 + hbase + l15] = hv[r];
        }
      }
      __syncthreads();  // h(t) visible in LDS
      // ---- ring store (packed, from LDS; all 16 waves participate) ----
      if (LAYER < 4) {
        int row = tid >> 6, cg = tid & 63;
        if (cg * 4 < H) {
          u64 v = *(const u64*)&hb[cur * 16 * HP + row * HP + cg * 4];
          store8_llc(rout + ((size_t)(rg * DSLOT + slot) * CCH + i) * 16 * H +
                         row * H + cg * 4, v);
        }
      }
    }
    __syncthreads();  // drain last ring stores (vmcnt(0) before barrier)
    if (tid == 0) {
      if (LAYER < 4)
        __hip_atomic_store(flag_ptr(flags, LAYER - 1, 0, rg), (unsigned)(k + 1),
                           __ATOMIC_RELAXED, __HIP_MEMORY_SCOPE_AGENT);
      if (LAYER > 1)
        __hip_atomic_store(flag_ptr(flags, LAYER - 2, 1, rg), (unsigned)(k + 1),
                           __ATOMIC_RELAXED, __HIP_MEMORY_SCOPE_AGENT);
    }
  }
}

struct KParams {
  const float* x;
  const float* W1; const float* U1; const float* b1;
  const float* W2; const float* U2; const float* b2;
  const float* W3; const float* U3; const float* b3;
  const float* W4; const float* U4; const float* b4;
  float* out;
  unsigned* flags;
  __bf16* ring0; __bf16* ring1; __bf16* ring2;   // L1->L2 (H256), L2->L3 (128), L3->L4 (256)
};

__global__ __launch_bounds__(1024, 4) void lstm_kernel(KParams p) {
  __shared__ __align__(16) char lds[32768 + 2 * 16 * 264 * 2];
  const int layer = blockIdx.x >> 2;
  const int rg = blockIdx.x & 3;
  if (layer == 0)
    layer_run<256, 256, 1>(p.x, nullptr, p.W1, p.U1, p.b1, p.ring0, nullptr,
                           p.flags, rg, lds);
  else if (layer == 1)
    layer_run<256, 128, 2>(nullptr, p.ring0, p.W2, p.U2, p.b2, p.ring1, nullptr,
                           p.flags, rg, lds);
  else if (layer == 2)
    layer_run<128, 256, 3>(nullptr, p.ring1, p.W3, p.U3, p.b3, p.ring2, nullptr,
                           p.flags, rg, lds);
  else
    layer_run<256, 256, 4>(nullptr, p.ring2, p.W4, p.U4, p.b4, nullptr, p.out,
                           p.flags, rg, lds);
}

extern "C" void kernel_launch(void* const* d_in, const int* in_sizes, int n_in,
                              void* d_out, int out_size, void* d_ws, size_t ws_size,
                              hipStream_t stream) {
  unsigned char* ws = (unsigned char*)d_ws;
  KParams p;
  p.x  = (const float*)d_in[0];
  p.W1 = (const float*)d_in[1];  p.U1 = (const float*)d_in[2];  p.b1 = (const float*)d_in[3];
  p.W2 = (const float*)d_in[4];  p.U2 = (const float*)d_in[5];  p.b2 = (const float*)d_in[6];
  p.W3 = (const float*)d_in[7];  p.U3 = (const float*)d_in[8];  p.b3 = (const float*)d_in[9];
  p.W4 = (const float*)d_in[10]; p.U4 = (const float*)d_in[11]; p.b4 = (const float*)d_in[12];
  p.out = (float*)d_out;
  p.flags = (unsigned*)ws;                         // flag lines in first 8 KB
  size_t off = 8192;
  // ring sizes: 4 rg * DSLOT * CCH * 16 rows * H cols * 2 B
  p.ring0 = (__bf16*)(ws + off); off += (size_t)4 * DSLOT * CCH * 16 * 256 * 2;
  p.ring1 = (__bf16*)(ws + off); off += (size_t)4 * DSLOT * CCH * 16 * 128 * 2;
  p.ring2 = (__bf16*)(ws + off); off += (size_t)4 * DSLOT * CCH * 16 * 256 * 2;

  hipMemsetAsync(d_ws, 0, 8192, stream);           // zero the chunk flags

  lstm_kernel<<<dim3(16), dim3(1024), 0, stream>>>(p);
}

// Round 6
// 7798.266 us; speedup vs baseline: 4.5145x; 4.5145x over previous
//
#include <hip/hip_runtime.h>
#include <hip/hip_bf16.h>

// LSTM autoencoder, 4 layers pipelined diagonally across timesteps.
// 56 pipeline WGs (as R4: neighbor-only flag waits, LLC-coherent relaxed
// atomics for h exchange, weights in register MFMA B-fragments) + 200 HEATER
// WGs running a dependent-FMA spin to hold the DPM clock up (hypothesis:
// 2%-active chip sits at ~450 MHz clock floor, inflating the per-step
// latency chain ~5x). Heaters poll a done flag and exit when L4 finishes.

typedef __bf16 bf16x8 __attribute__((ext_vector_type(8)));
typedef float f32x4 __attribute__((ext_vector_type(4)));
typedef unsigned long long u64;

#define NWG 56
#define NBLK 256
#define TSTEPS 1024
#define NSTEPS (TSTEPS + 3)
#define DONE_IDX 1024  // byte offset 4096 in ws (inside zeroed 8 KB)

__device__ __forceinline__ f32x4 mfma16(bf16x8 a, bf16x8 b, f32x4 c) {
  return __builtin_amdgcn_mfma_f32_16x16x32_bf16(a, b, c, 0, 0, 0);
}

__device__ __forceinline__ float sigmoid_fast(float x) {
  return 1.0f / (1.0f + __expf(-x));
}

// 16B MFMA A-fragment via two 8B LLC-coherent (agent-scope) atomic loads.
__device__ __forceinline__ bf16x8 load_frag_llc(const __bf16* p) {
  union { bf16x8 v; u64 d[2]; } u;
  u.d[0] = __hip_atomic_load((const u64*)p, __ATOMIC_RELAXED,
                             __HIP_MEMORY_SCOPE_AGENT);
  u.d[1] = __hip_atomic_load((const u64*)(p + 4), __ATOMIC_RELAXED,
                             __HIP_MEMORY_SCOPE_AGENT);
  return u.v;
}

__device__ __forceinline__ void store8_llc(__bf16* p, u64 v) {
  __hip_atomic_store((u64*)p, v, __ATOMIC_RELAXED, __HIP_MEMORY_SCOPE_AGENT);
}

// Wait until layers {LAYER-1, LAYER, LAYER+1} have all finished step s-1
// (flag >= s). All waves poll; <=40 lanes over <=3 cache lines.
template <int LAYER>
__device__ __forceinline__ void wait_deps(unsigned* flags, unsigned s) {
  constexpr int n1 = (LAYER >= 2) ? ((LAYER - 1 == 2) ? 8 : 16) : 0;
  constexpr int n2 = (LAYER == 2) ? 8 : 16;
  constexpr int n3 = (LAYER <= 3) ? ((LAYER + 1 == 2) ? 8 : 16) : 0;
  constexpr int b1 = (LAYER >= 2) ? (LAYER - 2) * 32 : 0;
  constexpr int b2 = (LAYER - 1) * 32;
  constexpr int b3 = (LAYER <= 3) ? LAYER * 32 : 0;
  const int lane = threadIdx.x & 63;
  int fidx;
  if (lane < n1) fidx = b1 + lane;
  else if (lane < n1 + n2) fidx = b2 + (lane - n1);
  else if (lane < n1 + n2 + n3) fidx = b3 + (lane - n1 - n2);
  else fidx = b2;  // duplicate a same-layer flag; harmless
  unsigned* p = &flags[fidx];
  while (true) {
    unsigned v = __hip_atomic_load(p, __ATOMIC_RELAXED,
                                   __HIP_MEMORY_SCOPE_AGENT);
    if (!__ballot(v < s)) break;
  }
}

// One LSTM layer, one gate-column slice (16 h-columns x 4 gates = 64 cols).
// Wave w handles batch rows [16w,16w+16). Each lane keeps c-state for its 4
// (row,hcol) cells; W/U fragments live in registers for the whole kernel.
template <int F, int H, int LAYER>
__device__ void layer_loop(const float* __restrict__ xg,   // LAYER==1: x [64][1024][256]
                           const __bf16* __restrict__ xin, // LAYER>1: prev h [2][64][F]
                           const float* __restrict__ W,    // [F][4H]
                           const float* __restrict__ U,    // [H][4H]
                           const float* __restrict__ bias_g, // [4H]
                           __bf16* __restrict__ hbuf,      // own h [2][64][H]
                           float* __restrict__ out,        // LAYER==4: [64][1024][256]
                           unsigned* flags, int slice, __bf16* smem) {
  constexpr int KW = F / 32;
  constexpr int KU = H / 32;
  constexpr int FOURH = 4 * H;
  constexpr int MYFLAG_BASE = (LAYER - 1) * 32;
  const int tid = threadIdx.x;
  const int wave = tid >> 6;
  const int lane = tid & 63;
  const int l15 = lane & 15;
  const int q = lane >> 4;
  const int hcol = slice * 16 + l15;
  const int brow = wave * 16;

  float bz[4];
#pragma unroll
  for (int nt = 0; nt < 4; ++nt) bz[nt] = bias_g[nt * H + hcol];

  // ---- one-time: stage W slice to LDS (coalesced), extract B-frags to regs ----
  bf16x8 wf[4][KW];
  bf16x8 uf[4][KU];
  for (int idx = tid; idx < F * 64; idx += 256) {
    int k = idx >> 6, c = idx & 63;
    int col = (c >> 4) * H + slice * 16 + (c & 15);
    smem[c * F + k] = (__bf16)W[k * FOURH + col];
  }
  __syncthreads();
#pragma unroll
  for (int nt = 0; nt < 4; ++nt)
#pragma unroll
    for (int kk = 0; kk < KW; ++kk)
      wf[nt][kk] = *(const bf16x8*)&smem[(nt * 16 + l15) * F + kk * 32 + q * 8];
  __syncthreads();
  for (int idx = tid; idx < H * 64; idx += 256) {
    int k = idx >> 6, c = idx & 63;
    int col = (c >> 4) * H + slice * 16 + (c & 15);
    smem[c * H + k] = (__bf16)U[k * FOURH + col];
  }
  __syncthreads();
#pragma unroll
  for (int nt = 0; nt < 4; ++nt)
#pragma unroll
    for (int kk = 0; kk < KU; ++kk)
      uf[nt][kk] = *(const bf16x8*)&smem[(nt * 16 + l15) * H + kk * 32 + q * 8];
  __syncthreads();

  // LDS region reused as 64x16 bf16 transpose tile for packed h stores.
  __bf16* hlds = smem;

  float c_state[4] = {0.f, 0.f, 0.f, 0.f};

  for (int s = 0; s < NSTEPS; ++s) {
    const int t = s - (LAYER - 1);
    const bool active = (t >= 0) & (t < TSTEPS);

    // Layer 1: x(t) has no cross-WG dependency -> load+convert BEFORE the
    // wait so HBM latency hides behind the flag poll.
    bf16x8 a_pre[(LAYER == 1) ? KW : 1];
    if (LAYER == 1 && active) {
      const float* xrow = xg + ((size_t)(brow + l15) * 1024 + t) * 256 + q * 8;
#pragma unroll
      for (int kk = 0; kk < KW; ++kk) {
        const float4* p4 = (const float4*)(xrow + kk * 32);
        float4 a0 = p4[0], a1 = p4[1];
        bf16x8 a;
        a[0] = (__bf16)a0.x; a[1] = (__bf16)a0.y;
        a[2] = (__bf16)a0.z; a[3] = (__bf16)a0.w;
        a[4] = (__bf16)a1.x; a[5] = (__bf16)a1.y;
        a[6] = (__bf16)a1.z; a[7] = (__bf16)a1.w;
        a_pre[kk] = a;
      }
    }

    wait_deps<LAYER>(flags, (unsigned)s);

    float hv[4];
    if (active) {
      f32x4 acc[4] = {};
      // ---- input projection: z += x(t) @ W ----
      if (LAYER == 1) {
#pragma unroll
        for (int kk = 0; kk < KW; ++kk)
#pragma unroll
          for (int nt = 0; nt < 4; ++nt)
            acc[nt] = mfma16(a_pre[kk], wf[nt][kk], acc[nt]);
      } else {
        const __bf16* xr = xin + ((size_t)(t & 1) * 64 + brow + l15) * F + q * 8;
#pragma unroll
        for (int kk = 0; kk < KW; ++kk) {
          bf16x8 a = load_frag_llc(xr + kk * 32);
#pragma unroll
          for (int nt = 0; nt < 4; ++nt) acc[nt] = mfma16(a, wf[nt][kk], acc[nt]);
        }
      }
      // ---- recurrent projection: z += h(t-1) @ U ----
      if (t > 0) {
        const __bf16* hr = hbuf + ((size_t)((t - 1) & 1) * 64 + brow + l15) * H + q * 8;
#pragma unroll
        for (int kk = 0; kk < KU; ++kk) {
          bf16x8 a = load_frag_llc(hr + kk * 32);
#pragma unroll
          for (int nt = 0; nt < 4; ++nt) acc[nt] = mfma16(a, uf[nt][kk], acc[nt]);
        }
      }
      // ---- gates + state update (all lane-local) ----
#pragma unroll
      for (int r = 0; r < 4; ++r) {
        float zi = acc[0][r] + bz[0];
        float zf = acc[1][r] + bz[1];
        float zg = acc[2][r] + bz[2];
        float zo = acc[3][r] + bz[3];
        float ig = sigmoid_fast(zi);
        float fg = sigmoid_fast(zf);
        float gg = fmaxf(zg, 0.0f);
        float og = sigmoid_fast(zo);
        float cn = fg * c_state[r] + ig * gg;
        c_state[r] = cn;
        hv[r] = og * fmaxf(cn, 0.0f);
        // stage into 64x16 LDS tile for packed 8B coherent stores
        hlds[(brow + q * 4 + r) * 16 + l15] = (__bf16)hv[r];
      }
    }
    __syncthreads();  // A: transpose tile visible
    if (active) {
      // packed h store: thread tid owns row tid/4, col-group tid%4 (4 bf16)
      int row = tid >> 2, cg = tid & 3;
      u64 v = *(const u64*)&hlds[row * 16 + cg * 4];
      store8_llc(hbuf + ((size_t)(t & 1) * 64 + row) * H + slice * 16 + cg * 4, v);
    }
    __syncthreads();  // B: all waves' h stores vmcnt-drained (at LLC)
    if (tid == 0)
      __hip_atomic_store(&flags[MYFLAG_BASE + slice], (unsigned)(s + 1),
                         __ATOMIC_RELAXED, __HIP_MEMORY_SCOPE_AGENT);
    // Layer 4 output: fire-and-forget AFTER the post; drains during the
    // next step's slack instead of sitting on the critical chain.
    if (LAYER == 4 && active) {
#pragma unroll
      for (int r = 0; r < 4; ++r) {
        int b = brow + q * 4 + r;
        out[((size_t)b * 1024 + t) * 256 + hcol] = hv[r];
      }
    }
  }
}

// Dependent-FMA spin: keeps the CU "busy" (DPM clock up) at low power
// (1 VALU issue / ~4 cyc). Polls done flag every 2048 FMAs.
__device__ void heater(unsigned* done, float* sink) {
  float v = (float)(threadIdx.x + 1) * 1e-8f;
  while (true) {
#pragma unroll 16
    for (int i = 0; i < 2048; ++i) v = __builtin_fmaf(v, 1.0000001f, 1.0e-9f);
    unsigned d = __hip_atomic_load(done, __ATOMIC_RELAXED,
                                   __HIP_MEMORY_SCOPE_AGENT);
    if (d) break;
  }
  if (v == 0.123456f && threadIdx.x == 0) *sink = v;  // keep v alive
}

struct KParams {
  const float* x;
  const float* W1; const float* U1; const float* b1;
  const float* W2; const float* U2; const float* b2;
  const float* W3; const float* U3; const float* b3;
  const float* W4; const float* U4; const float* b4;
  float* out;
  unsigned* flags;
  void* h1; void* h2; void* h3; void* h4;
};

__global__ __launch_bounds__(256, 1) void lstm_kernel(KParams p) {
  __shared__ __align__(16) __bf16 smem[64 * 256];  // 32 KB staging
  int wg = blockIdx.x;
  if (wg >= NWG) {
    heater(&p.flags[DONE_IDX], (float*)&p.flags[DONE_IDX + 32]);
    return;
  }
  if (wg < 16)
    layer_loop<256, 256, 1>(p.x, nullptr, p.W1, p.U1, p.b1, (__bf16*)p.h1,
                            nullptr, p.flags, wg, smem);
  else if (wg < 24)
    layer_loop<256, 128, 2>(nullptr, (const __bf16*)p.h1, p.W2, p.U2, p.b2,
                            (__bf16*)p.h2, nullptr, p.flags, wg - 16, smem);
  else if (wg < 40)
    layer_loop<128, 256, 3>(nullptr, (const __bf16*)p.h2, p.W3, p.U3, p.b3,
                            (__bf16*)p.h3, nullptr, p.flags, wg - 24, smem);
  else {
    layer_loop<256, 256, 4>(nullptr, (const __bf16*)p.h3, p.W4, p.U4, p.b4,
                            (__bf16*)p.h4, p.out, p.flags, wg - 40, smem);
    if (threadIdx.x == 0)
      __hip_atomic_store(&p.flags[DONE_IDX], 1u, __ATOMIC_RELAXED,
                         __HIP_MEMORY_SCOPE_AGENT);
  }
}

extern "C" void kernel_launch(void* const* d_in, const int* in_sizes, int n_in,
                              void* d_out, int out_size, void* d_ws, size_t ws_size,
                              hipStream_t stream) {
  unsigned char* ws = (unsigned char*)d_ws;
  KParams p;
  p.x  = (const float*)d_in[0];
  p.W1 = (const float*)d_in[1];  p.U1 = (const float*)d_in[2];  p.b1 = (const float*)d_in[3];
  p.W2 = (const float*)d_in[4];  p.U2 = (const float*)d_in[5];  p.b2 = (const float*)d_in[6];
  p.W3 = (const float*)d_in[7];  p.U3 = (const float*)d_in[8];  p.b3 = (const float*)d_in[9];
  p.W4 = (const float*)d_in[10]; p.U4 = (const float*)d_in[11]; p.b4 = (const float*)d_in[12];
  p.out = (float*)d_out;
  p.flags = (unsigned*)ws;                 // flag lines + done flag in 8 KB
  size_t off = 8192;
  p.h1 = (void*)(ws + off); off += (size_t)2 * 64 * 256 * 2;
  p.h2 = (void*)(ws + off); off += (size_t)2 * 64 * 128 * 2;
  p.h3 = (void*)(ws + off); off += (size_t)2 * 64 * 256 * 2;
  p.h4 = (void*)(ws + off);

  hipMemsetAsync(d_ws, 0, 8192, stream);   // zero flags + done

  lstm_kernel<<<dim3(NBLK), dim3(256), 0, stream>>>(p);
}

// Round 7
// 7517.760 us; speedup vs baseline: 4.6829x; 1.0373x over previous
//
#include <hip/hip_runtime.h>
#include <hip/hip_bf16.h>

// LSTM autoencoder, 4 layers, 56 persistent WGs, self-timed dataflow.
// h exchange through depth-64 per-layer global rings; consumers poll the
// DATA itself (0xFFFF bf16 = NaN sentinel, unreachable: h always finite).
// No flags/fences/barriers on the critical path. Ring reuse: producer
// NaNs slot t+1 during step t (drained by S1); cross-layer overwrite gated
// by a consumed-flag checked every 16 steps with 32-step slack.

typedef __bf16 bf16x8 __attribute__((ext_vector_type(8)));
typedef float f32x4 __attribute__((ext_vector_type(4)));
typedef unsigned long long u64;

#define NWG 56
#define TSTEPS 1024
#define RDEPTH 64
#define SENT (~0ull)

__device__ __forceinline__ f32x4 mfma16(bf16x8 a, bf16x8 b, f32x4 c) {
  return __builtin_amdgcn_mfma_f32_16x16x32_bf16(a, b, c, 0, 0, 0);
}
__device__ __forceinline__ float sigmoid_fast(float x) {
  return 1.0f / (1.0f + __expf(-x));
}
__device__ __forceinline__ u64 load8_llc(const __bf16* p) {
  return __hip_atomic_load((const u64*)p, __ATOMIC_RELAXED,
                           __HIP_MEMORY_SCOPE_AGENT);
}
__device__ __forceinline__ void store8_llc(__bf16* p, u64 v) {
  __hip_atomic_store((u64*)p, v, __ATOMIC_RELAXED, __HIP_MEMORY_SCOPE_AGENT);
}
__device__ __forceinline__ bf16x8 frag_of(u64 lo, u64 hi) {
  union { bf16x8 v; u64 d[2]; } u; u.d[0] = lo; u.d[1] = hi; return u.v;
}

// One layer, one 16-hcol slice. Wave w: batch rows [16w,16w+16).
// NDOWN = # downstream consumer WGs of this layer's ring (0 for L4).
template <int F, int H, int LAYER, int NDOWN>
__device__ void layer_run(const float* __restrict__ xg,   // L1: x [64][1024][256]
                          const __bf16* __restrict__ rin, // L>1: prev ring
                          const float* __restrict__ W, const float* __restrict__ U,
                          const float* __restrict__ bias,
                          __bf16* __restrict__ rout,      // own ring [64][64][H]
                          float* __restrict__ out,        // L4
                          unsigned* flags, int slice, __bf16* smem) {
  constexpr int KW = F / 32;
  constexpr int KU = H / 32;
  constexpr int FOURH = 4 * H;
  const int tid = threadIdx.x;
  const int wave = tid >> 6;
  const int lane = tid & 63;
  const int l15 = lane & 15;
  const int q = lane >> 4;
  const int hcol = slice * 16 + l15;
  const int brow = wave * 16;
  const int srow = tid >> 2, scg = tid & 3;   // packed-store mapping

  float bz[4];
#pragma unroll
  for (int nt = 0; nt < 4; ++nt) bz[nt] = bias[nt * H + hcol];

  // ---- one-time: stage W,U slice to LDS, extract B-frags to registers ----
  bf16x8 wf[4][KW];
  bf16x8 uf[4][KU];
  for (int idx = tid; idx < F * 64; idx += 256) {
    int k = idx >> 6, c = idx & 63;
    int col = (c >> 4) * H + slice * 16 + (c & 15);
    smem[c * F + k] = (__bf16)W[k * FOURH + col];
  }
  __syncthreads();
#pragma unroll
  for (int nt = 0; nt < 4; ++nt)
#pragma unroll
    for (int kk = 0; kk < KW; ++kk)
      wf[nt][kk] = *(const bf16x8*)&smem[(nt * 16 + l15) * F + kk * 32 + q * 8];
  __syncthreads();
  for (int idx = tid; idx < H * 64; idx += 256) {
    int k = idx >> 6, c = idx & 63;
    int col = (c >> 4) * H + slice * 16 + (c & 15);
    smem[c * H + k] = (__bf16)U[k * FOURH + col];
  }
  __syncthreads();
#pragma unroll
  for (int nt = 0; nt < 4; ++nt)
#pragma unroll
    for (int kk = 0; kk < KU; ++kk)
      uf[nt][kk] = *(const bf16x8*)&smem[(nt * 16 + l15) * H + kk * 32 + q * 8];
  __syncthreads();

  __bf16* hlds = smem;  // reused as 64x16 transpose tile

  float c_state[4] = {0.f, 0.f, 0.f, 0.f};

  for (int t = 0; t < TSTEPS; ++t) {
    // ---- cross-layer anti-dep gate, every 16 steps (off critical path) ----
    if (NDOWN > 0 && (t & 15) == 0 && t >= 48) {
      if (wave == 0) {
        const bool act = lane < NDOWN;
        unsigned* fp = &flags[((LAYER - 1) * 16 + (act ? lane : 0)) * 32];
        while (true) {
          unsigned v = __hip_atomic_load(fp, __ATOMIC_RELAXED,
                                         __HIP_MEMORY_SCOPE_AGENT);
          if (!__ballot(act && (int)v < t - 32)) break;
        }
      }
      __syncthreads();
    }
    // ---- NaN-init own region of slot t+1 (reused after full ring cycle) ----
    store8_llc(rout + ((size_t)((t + 1) & (RDEPTH - 1))) * 64 * H + srow * H +
                   slice * 16 + scg * 4, SENT);
    __syncthreads();  // S1: drains NaN before data(t) store can be observed

    // ---- inputs: x (L1, plain loads) / xin ring + recurrence ring, NaN-poll ----
    float4 xf[(LAYER == 1) ? 2 * KW : 1];
    if (LAYER == 1) {
      const float* xrow = xg + ((size_t)(brow + l15) * 1024 + t) * 256 + q * 8;
#pragma unroll
      for (int kk = 0; kk < KW; ++kk) {
        const float4* p4 = (const float4*)(xrow + kk * 32);
        xf[2 * kk] = p4[0];
        xf[2 * kk + 1] = p4[1];
      }
    }
    u64 rh[2 * KU];
    u64 rx[(LAYER > 1) ? 2 * KW : 2];
    const bool needr = (t > 0);
    const __bf16* rr = rout + ((size_t)((t - 1) & (RDEPTH - 1))) * 64 * H +
                       (brow + l15) * H + q * 8;
    const __bf16* xr = (LAYER > 1)
        ? rin + ((size_t)(t & (RDEPTH - 1))) * 64 * F + (brow + l15) * F + q * 8
        : nullptr;
    if (needr || LAYER > 1) {
      while (true) {
        bool bad = false;
        if (needr) {
#pragma unroll
          for (int kk = 0; kk < KU; ++kk) {
            rh[2 * kk] = load8_llc(rr + kk * 32);
            rh[2 * kk + 1] = load8_llc(rr + kk * 32 + 4);
          }
        }
        if (LAYER > 1) {
#pragma unroll
          for (int kk = 0; kk < KW; ++kk) {
            rx[2 * kk] = load8_llc(xr + kk * 32);
            rx[2 * kk + 1] = load8_llc(xr + kk * 32 + 4);
          }
        }
        if (needr) {
#pragma unroll
          for (int j = 0; j < 2 * KU; ++j) bad |= (rh[j] == SENT);
        }
        if (LAYER > 1) {
#pragma unroll
          for (int j = 0; j < 2 * KW; ++j) bad |= (rx[j] == SENT);
        }
        if (!__ballot(bad)) break;
      }
    }

    // ---- MFMA chain ----
    f32x4 acc[4] = {};
#pragma unroll
    for (int kk = 0; kk < KW; ++kk) {
      bf16x8 a;
      if (LAYER == 1) {
        float4 a0 = xf[2 * kk], a1 = xf[2 * kk + 1];
        a[0] = (__bf16)a0.x; a[1] = (__bf16)a0.y;
        a[2] = (__bf16)a0.z; a[3] = (__bf16)a0.w;
        a[4] = (__bf16)a1.x; a[5] = (__bf16)a1.y;
        a[6] = (__bf16)a1.z; a[7] = (__bf16)a1.w;
      } else {
        a = frag_of(rx[2 * kk], rx[2 * kk + 1]);
      }
#pragma unroll
      for (int nt = 0; nt < 4; ++nt) acc[nt] = mfma16(a, wf[nt][kk], acc[nt]);
    }
    if (needr) {
#pragma unroll
      for (int kk = 0; kk < KU; ++kk) {
        bf16x8 a = frag_of(rh[2 * kk], rh[2 * kk + 1]);
#pragma unroll
        for (int nt = 0; nt < 4; ++nt) acc[nt] = mfma16(a, uf[nt][kk], acc[nt]);
      }
    }

    // ---- gates + state update (lane-local) ----
    float hv[4];
#pragma unroll
    for (int r = 0; r < 4; ++r) {
      float zi = acc[0][r] + bz[0];
      float zf = acc[1][r] + bz[1];
      float zg = acc[2][r] + bz[2];
      float zo = acc[3][r] + bz[3];
      float ig = sigmoid_fast(zi);
      float fg = sigmoid_fast(zf);
      float gg = fmaxf(zg, 0.0f);
      float og = sigmoid_fast(zo);
      float cn = fg * c_state[r] + ig * gg;
      c_state[r] = cn;
      hv[r] = og * fmaxf(cn, 0.0f);
      hlds[(brow + q * 4 + r) * 16 + l15] = (__bf16)hv[r];
    }
    __syncthreads();  // S2: transpose tile complete

    // ---- packed data store into own ring slot t — visibility IS the signal ----
    {
      u64 v = *(const u64*)&hlds[srow * 16 + scg * 4];
      store8_llc(rout + ((size_t)(t & (RDEPTH - 1))) * 64 * H + srow * H +
                     slice * 16 + scg * 4, v);
    }
    if (LAYER == 4) {
#pragma unroll
      for (int r = 0; r < 4; ++r) {
        int b = brow + q * 4 + r;
        out[((size_t)b * 1024 + t) * 256 + hcol] = hv[r];
      }
    }
    // ---- consumed post for upstream producer (every 16 steps) ----
    if (LAYER > 1 && (t & 15) == 15 && tid == 0)
      __hip_atomic_store(&flags[((LAYER - 2) * 16 + slice) * 32],
                         (unsigned)(t + 1), __ATOMIC_RELAXED,
                         __HIP_MEMORY_SCOPE_AGENT);
  }
}

struct KParams {
  const float* x;
  const float* W1; const float* U1; const float* b1;
  const float* W2; const float* U2; const float* b2;
  const float* W3; const float* U3; const float* b3;
  const float* W4; const float* U4; const float* b4;
  float* out;
  unsigned* flags;
  __bf16* r1; __bf16* r2; __bf16* r3; __bf16* r4;
};

__global__ __launch_bounds__(256, 1) void lstm_kernel(KParams p) {
  __shared__ __align__(16) __bf16 smem[64 * 256];  // 32 KB staging
  int wg = blockIdx.x;
  if (wg < 16)
    layer_run<256, 256, 1, 8>(p.x, nullptr, p.W1, p.U1, p.b1, p.r1, nullptr,
                              p.flags, wg, smem);
  else if (wg < 24)
    layer_run<256, 128, 2, 16>(nullptr, p.r1, p.W2, p.U2, p.b2, p.r2, nullptr,
                               p.flags, wg - 16, smem);
  else if (wg < 40)
    layer_run<128, 256, 3, 16>(nullptr, p.r2, p.W3, p.U3, p.b3, p.r3, nullptr,
                               p.flags, wg - 24, smem);
  else
    layer_run<256, 256, 4, 0>(nullptr, p.r3, p.W4, p.U4, p.b4, p.r4, p.out,
                              p.flags, wg - 40, smem);
}

extern "C" void kernel_launch(void* const* d_in, const int* in_sizes, int n_in,
                              void* d_out, int out_size, void* d_ws, size_t ws_size,
                              hipStream_t stream) {
  unsigned char* ws = (unsigned char*)d_ws;
  KParams p;
  p.x  = (const float*)d_in[0];
  p.W1 = (const float*)d_in[1];  p.U1 = (const float*)d_in[2];  p.b1 = (const float*)d_in[3];
  p.W2 = (const float*)d_in[4];  p.U2 = (const float*)d_in[5];  p.b2 = (const float*)d_in[6];
  p.W3 = (const float*)d_in[7];  p.U3 = (const float*)d_in[8];  p.b3 = (const float*)d_in[9];
  p.W4 = (const float*)d_in[10]; p.U4 = (const float*)d_in[11]; p.b4 = (const float*)d_in[12];
  p.out = (float*)d_out;
  p.flags = (unsigned*)ws;                  // consumed flags, first 16 KB
  size_t off = 16384;
  const size_t rbytes256 = (size_t)RDEPTH * 64 * 256 * 2;   // 2 MB
  const size_t rbytes128 = (size_t)RDEPTH * 64 * 128 * 2;   // 1 MB
  p.r1 = (__bf16*)(ws + off); off += rbytes256;
  p.r2 = (__bf16*)(ws + off); off += rbytes128;
  p.r3 = (__bf16*)(ws + off); off += rbytes256;
  p.r4 = (__bf16*)(ws + off); off += rbytes256;

  hipMemsetAsync(ws, 0, 16384, stream);                    // zero consumed flags
  hipMemsetAsync(ws + 16384, 0xFF, off - 16384, stream);   // NaN all ring slots

  lstm_kernel<<<dim3(NWG), dim3(256), 0, stream>>>(p);
}